// Round 1
// baseline (536.782 us; speedup 1.0000x reference)
//
#include <hip/hip_runtime.h>

// Autoregressive linear model, restructured as:
//   A[b,j,d]  = bias[d] + sum_{t=j}^{2047} y[b,t,d] * W[t-j,d]     (K2, parallel correlation)
//   c[m,d]    = W[2048-m,d], m=1..255
//   h[0]=1; h[i] = sum_{m=1}^{i} c[m]*h[i-m]                        (K1, tiny sequential)
//   out[b,i,d]= sum_{s=0}^{i} A[b,s,d]*h[i-s,d]                     (K3, parallel causal conv)
// Exact reformulation of the reference scan (verified for i=0,1 by hand).

#define B_SZ   512
#define L_SZ   2048
#define D_SZ   32
#define NI_SZ  256
#define WEXT_N 2304           // wext row length per d (index kk = t - j + 255 in [0,2304))
#define ST_W   324            // LDS stride for w segment rows (>=320, mult of 4, !=0 mod 32 pattern)
#define ST_Y   65             // LDS stride for y rows (odd -> conflict-free across d)
#define ST_H   265            // LDS stride for h rows (odd), 8 front pad + 256 + 1

// ---------------- K0: build zero-padded weight rows wext[d][kk] ----------------
// wext[d][kk] = (kk>=255 && kk-255<2048) ? W[(kk-255)*32 + d] : 0
__global__ __launch_bounds__(256) void k0_wext(const float* __restrict__ W,
                                               float* __restrict__ wext) {
    int ch = blockIdx.x;          // 0..8
    int d  = blockIdx.y;          // 0..31
    int kk = ch * 256 + threadIdx.x;
    if (kk >= WEXT_N) return;
    int t = kk - 255;
    float v = 0.f;
    if (t >= 0 && t < L_SZ) v = W[t * D_SZ + d];
    wext[d * WEXT_N + kk] = v;
}

// ---------------- K1: impulse response h[d][0..255] ----------------
// One wave (64 threads) per d. Lane j owns positions j, j+64, j+128, j+192.
// Forward substitution with broadcast of each finalized h_i via shfl.
__global__ __launch_bounds__(64) void k1_h(const float* __restrict__ W,
                                           float* __restrict__ h_g) {
    int d = blockIdx.x;
    int lane = threadIdx.x;
    __shared__ float c_l[256];    // c[m] = W[2048-m][d], c[0] unused (=0)
#pragma unroll
    for (int k = 0; k < 4; ++k) {
        int m = lane + 64 * k;
        c_l[m] = (m >= 1) ? W[(L_SZ - m) * D_SZ + d] : 0.f;
    }
    __syncthreads();
    float s0 = 0.f, s1 = 0.f, s2 = 0.f, s3 = 0.f;
    for (int i = 0; i < 256; ++i) {
        int slot = i >> 6;
        float v = (slot == 0) ? s0 : (slot == 1) ? s1 : (slot == 2) ? s2 : s3;
        float hv = (i == 0) ? 1.f : __shfl(v, i & 63, 64);
        int j;
        j = lane;        if (j > i) s0 += c_l[j - i] * hv;
        j = lane + 64;   if (j > i) s1 += c_l[j - i] * hv;
        j = lane + 128;  if (j > i) s2 += c_l[j - i] * hv;
        j = lane + 192;  if (j > i) s3 += c_l[j - i] * hv;
    }
    h_g[d * 256 + lane]       = (lane == 0) ? 1.f : s0;
    h_g[d * 256 + lane + 64]  = s1;
    h_g[d * 256 + lane + 128] = s2;
    h_g[d * 256 + lane + 192] = s3;
}

// ---------------- K2: big correlation A[b][i][d] -> d_out ----------------
// One block per b (512 blocks). 256 threads = 32 d * 8 i-groups; thread owns
// 32 consecutive i (acc[32]). K-loop over t in chunks of 64, staging
// y[b,t0:t0+64,:] (contiguous 8KB) and wext[d][t0:t0+320] into LDS.
__global__ __launch_bounds__(256) void k2_corr(const float* __restrict__ Y,
                                               const float* __restrict__ wext,
                                               const float* __restrict__ bias,
                                               float* __restrict__ Aout) {
    __shared__ float w_seg[D_SZ * ST_W];   // 41.5 KB
    __shared__ float y_seg[D_SZ * ST_Y];   // 8.3 KB
    int b   = blockIdx.x;
    int tid = threadIdx.x;
    int d   = tid & 31;
    int ig  = tid >> 5;          // 0..7
    int ib  = ig * 32;           // first i of this thread
    float acc[32];
#pragma unroll
    for (int ii = 0; ii < 32; ++ii) acc[ii] = 0.f;
    const size_t ybase = (size_t)b * (L_SZ * D_SZ);

    for (int t0 = 0; t0 < L_SZ; t0 += 64) {
        __syncthreads();   // protect LDS reuse from previous chunk
        // stage y: 64 t * 32 d = 512 float4, 2 per thread, fully coalesced
        {
            int lin = tid;
#pragma unroll
            for (int it = 0; it < 2; ++it, lin += 256) {
                int dq = lin & 7, tt = lin >> 3;
                float4 v = *(const float4*)(Y + ybase + (size_t)(t0 + tt) * D_SZ + dq * 4);
                y_seg[(dq * 4 + 0) * ST_Y + tt] = v.x;
                y_seg[(dq * 4 + 1) * ST_Y + tt] = v.y;
                y_seg[(dq * 4 + 2) * ST_Y + tt] = v.z;
                y_seg[(dq * 4 + 3) * ST_Y + tt] = v.w;
            }
        }
        // stage w segment: w_seg[d][j] = wext[d][t0 + j], j in [0,320)
        {
            int dd = tid >> 3, jq8 = tid & 7;
#pragma unroll
            for (int q = 0; q < 10; ++q) {
                int jq = jq8 + q * 8;  // 0..79
                float4 v = *(const float4*)(wext + dd * WEXT_N + t0 + jq * 4);
                *(float4*)(&w_seg[dd * ST_W + jq * 4]) = v;
            }
        }
        __syncthreads();
        // compute: j_abs(t,i) = t + 255 - i; j_rel = j_abs - t0
#pragma unroll 2
        for (int tq = 0; tq < 16; ++tq) {
            float yv[4];
#pragma unroll
            for (int dt = 0; dt < 4; ++dt) yv[dt] = y_seg[d * ST_Y + tq * 4 + dt];
            float wv[36];
#pragma unroll
            for (int q = 0; q < 9; ++q)
                *(float4*)(&wv[q * 4]) =
                    *(const float4*)(&w_seg[d * ST_W + tq * 4 + 224 - ib + q * 4]);
            // wv[0] corresponds to j_rel = tq*4 + 224 - ib; offset(dt,ii) = dt + 31 - ii
#pragma unroll
            for (int dt = 0; dt < 4; ++dt)
#pragma unroll
                for (int ii = 0; ii < 32; ++ii)
                    acc[ii] += yv[dt] * wv[dt + 31 - ii];
        }
    }
    float bv = bias[d];
#pragma unroll
    for (int ii = 0; ii < 32; ++ii) {
        int i = ib + ii;
        Aout[(size_t)b * (NI_SZ * D_SZ) + i * D_SZ + d] = acc[ii] + bv;
    }
}

// ---------------- K3: out = h (*) A, in-place on d_out ----------------
// Block = (b, d-half of 16). Stage A[b][:, d-half] and h rows into LDS, then
// each thread runs 8 i's with a register ring of h (front zero-pad kills the
// triangular boundary; no masking needed).
__global__ __launch_bounds__(256) void k3_conv(const float* __restrict__ h_g,
                                               float* __restrict__ OutA) {
    __shared__ float A_l[256 * 16];   // 16 KB, [s][dd]
    __shared__ float h_l[16 * ST_H];  // 17 KB, [dd][8 zero pad + 256]
    int b  = blockIdx.x;
    int d0 = blockIdx.y * 16;
    int tid = threadIdx.x;
    // stage A (float4 over d-quads)
#pragma unroll
    for (int it = 0; it < 4; ++it) {
        int lin4 = tid + it * 256;          // 0..1023
        int dq = lin4 & 3, s = lin4 >> 2;   // s 0..255
        *(float4*)(&A_l[s * 16 + dq * 4]) =
            *(const float4*)(OutA + (size_t)b * (NI_SZ * D_SZ) + s * D_SZ + d0 + dq * 4);
    }
    // stage h
#pragma unroll
    for (int it = 0; it < 16; ++it) {
        int lin = tid + it * 256;           // 0..4095
        int dd = lin >> 8, m = lin & 255;
        h_l[dd * ST_H + 8 + m] = h_g[(d0 + dd) * 256 + m];
    }
    if (tid < 128) { int dd = tid >> 3, r = tid & 7; h_l[dd * ST_H + r] = 0.f; }
    __syncthreads();

    int d = tid & 15, grp = tid >> 4;       // 16 d * 16 groups
#pragma unroll 1
    for (int p = 0; p < 2; ++p) {
        int base = p * 128 + grp * 8;       // first i of this octet
        float w[8], acc[8];
#pragma unroll
        for (int r = 0; r < 8; ++r) { w[r] = h_l[d * ST_H + 8 + base + r]; acc[r] = 0.f; }
        int smax = base + 8;                // multiple of 8 -> clean unroll
#pragma unroll 8
        for (int s = 0; s < smax; ++s) {
            float Av = A_l[s * 16 + d];
#pragma unroll
            for (int r = 0; r < 8; ++r) acc[r] += Av * w[r];
            float nh = h_l[d * ST_H + 8 + base - s - 1];   // >=0; pad region -> 0
#pragma unroll
            for (int r = 7; r >= 1; --r) w[r] = w[r - 1];
            w[0] = nh;
        }
#pragma unroll
        for (int r = 0; r < 8; ++r)
            OutA[(size_t)b * (NI_SZ * D_SZ) + (base + r) * D_SZ + (d0 + d)] = acc[r];
    }
}

extern "C" void kernel_launch(void* const* d_in, const int* in_sizes, int n_in,
                              void* d_out, int out_size, void* d_ws, size_t ws_size,
                              hipStream_t stream) {
    const float* y_c  = (const float*)d_in[0];   // [512][2048][32]
    const float* W    = (const float*)d_in[1];   // [2048][32]
    const float* bias = (const float*)d_in[2];   // [32]
    float* out = (float*)d_out;                  // [512][256][32]
    float* ws  = (float*)d_ws;
    float* wext = ws;                 // 32*2304 floats = 294912 B
    float* h_g  = ws + 32 * WEXT_N;   // 32*256 floats  =  32768 B  (total < 330 KB)

    k0_wext<<<dim3(9, 32), 256, 0, stream>>>(W, wext);
    k1_h   <<<32, 64, 0, stream>>>(W, h_g);
    k2_corr<<<B_SZ, 256, 0, stream>>>(y_c, wext, bias, out);
    k3_conv<<<dim3(B_SZ, 2), 256, 0, stream>>>(h_g, out);
}

// Round 2
// 366.888 us; speedup vs baseline: 1.4631x; 1.4631x over previous
//
#include <hip/hip_runtime.h>

// Autoregressive linear model via LTI decomposition + bf16 MFMA:
//   Araw[b,i,d] = sum_t y[b,t,d] * W[t-i,d]          (k_gemm: 32 per-d GEMMs, MFMA)
//   h_d: impulse response of out_i = A_i + sum c_m out_{i-m}, c_m = W[2048-m]
//   out[b,i,d]  = sum_{m<=i} h_d[m]*Araw[b,i-m,d] + bias_d * cumsum(h_d)[i]
//
// ws layout (bytes):
//   Yt   [32][512][2048] bf16   @ 0          (67,108,864)
//   Bf   [32][64][16][64][8] bf16 @ 67108864 (33,554,432)  MFMA B-fragments
//   tmp  [2][32][512][256] f32  @ 100663296  (33,554,432)  k-split partials
//   h_g  [32][256] f32          @ 134217728  (32,768)
//   Hb   [32][256] f32          @ 134250496  (32,768)
// total 134,283,264 B (~128.1 MiB)

#define L_SZ   2048
#define D_SZ   32
#define NI_SZ  256

using frag_ab = __attribute__((ext_vector_type(8))) short;   // 8 bf16
using f32x4v  = __attribute__((ext_vector_type(4))) float;

__device__ inline ushort f2bf(float x) {
    uint32_t u = __float_as_uint(x);
    return (ushort)((u + 0x7fffu + ((u >> 16) & 1u)) >> 16);   // RTNE
}

// ---------------- k_trans: Y[b][t][d] f32 -> Yt[d][b][t] bf16 ----------------
// tile = 8 b x 64 t x 32 d. LDS rows r = bb*32 + d, 72 ushorts each, 16B-chunk
// XOR swizzle (chunk ^= r&7) for bank spread on b128 ops.
__global__ __launch_bounds__(256, 4) void k_trans(const float* __restrict__ Y,
                                                  ushort* __restrict__ Yt) {
    __shared__ ushort sm[256 * 72];   // 36.9 KB
    int b0 = blockIdx.x * 8, t0 = blockIdx.y * 64;
    int tid = threadIdx.x;
#pragma unroll
    for (int it = 0; it < 2; ++it) {
        int g = tid + it * 256;            // 0..511
        int dq = g & 7, bb = (g >> 3) & 7, tg = g >> 6;
        float4 v[8];
#pragma unroll
        for (int q = 0; q < 8; ++q)
            v[q] = *(const float4*)(Y + ((size_t)(b0 + bb) * L_SZ + t0 + tg * 8 + q) * D_SZ + dq * 4);
#pragma unroll
        for (int c = 0; c < 4; ++c) {
            int r = bb * 32 + dq * 4 + c;
            uint4 u;
            u.x = (uint)f2bf((&v[0].x)[c]) | ((uint)f2bf((&v[1].x)[c]) << 16);
            u.y = (uint)f2bf((&v[2].x)[c]) | ((uint)f2bf((&v[3].x)[c]) << 16);
            u.z = (uint)f2bf((&v[4].x)[c]) | ((uint)f2bf((&v[5].x)[c]) << 16);
            u.w = (uint)f2bf((&v[6].x)[c]) | ((uint)f2bf((&v[7].x)[c]) << 16);
            *(uint4*)&sm[r * 72 + ((tg ^ (r & 7)) * 8)] = u;
        }
    }
    __syncthreads();
#pragma unroll
    for (int ot = 0; ot < 8; ++ot) {
        int o = tid + ot * 256;            // 0..2047
        int ch = o & 7, r = o >> 3;        // r = bb*32 + d
        int bb = r >> 5, dd = r & 31;
        uint4 u = *(uint4*)&sm[r * 72 + ((ch ^ (r & 7)) * 8)];
        *(uint4*)(Yt + (size_t)(dd * 512 + b0 + bb) * L_SZ + t0 + ch * 8) = u;
    }
}

// ---------------- k_bfrag: Toeplitz B in MFMA-fragment order ----------------
// frag(d,kt,nt): lane l: n=l&15, quad=l>>4; j=0..7: k=kt*32+quad*8+j, i=nt*16+n,
// val = (0<=k-i<2048) ? W[(k-i)*32+d] : 0.
__global__ __launch_bounds__(256) void k_bfrag(const float* __restrict__ W,
                                               ushort* __restrict__ Bf) {
    int kt = blockIdx.x, d = blockIdx.y;
    int tid = threadIdx.x;
#pragma unroll
    for (int it = 0; it < 4; ++it) {
        int lin = tid + it * 256;          // 0..1023
        int lane = lin & 63, nt = lin >> 6;
        int n = lane & 15, quad = lane >> 4;
        int i = nt * 16 + n;
        ushort s[8];
#pragma unroll
        for (int j = 0; j < 8; ++j) {
            int k = kt * 32 + quad * 8 + j;
            int t = k - i;
            float v = (t >= 0 && t < L_SZ) ? W[t * D_SZ + d] : 0.f;
            s[j] = f2bf(v);
        }
        uint4 u;
        u.x = (uint)s[0] | ((uint)s[1] << 16);
        u.y = (uint)s[2] | ((uint)s[3] << 16);
        u.z = (uint)s[4] | ((uint)s[5] << 16);
        u.w = (uint)s[6] | ((uint)s[7] << 16);
        *(uint4*)(Bf + ((size_t)((d * 64 + kt) * 16 + nt) * 64 + lane) * 8) = u;
    }
}

// ---------------- k1: impulse response h + Hb = bias*cumsum(h) ----------------
__global__ __launch_bounds__(64) void k1_h(const float* __restrict__ W,
                                           const float* __restrict__ bias,
                                           float* __restrict__ h_g,
                                           float* __restrict__ Hb) {
    int d = blockIdx.x;
    int lane = threadIdx.x;
    __shared__ float c_l[256];
    __shared__ float h_l[256];
#pragma unroll
    for (int k = 0; k < 4; ++k) {
        int m = lane + 64 * k;
        c_l[m] = (m >= 1) ? W[(L_SZ - m) * D_SZ + d] : 0.f;
    }
    __syncthreads();
    float s0 = 0.f, s1 = 0.f, s2 = 0.f, s3 = 0.f;
    for (int i = 0; i < 256; ++i) {
        int slot = i >> 6;
        float v = (slot == 0) ? s0 : (slot == 1) ? s1 : (slot == 2) ? s2 : s3;
        float hv = (i == 0) ? 1.f : __shfl(v, i & 63, 64);
        int j;
        j = lane;        if (j > i) s0 += c_l[j - i] * hv;
        j = lane + 64;   if (j > i) s1 += c_l[j - i] * hv;
        j = lane + 128;  if (j > i) s2 += c_l[j - i] * hv;
        j = lane + 192;  if (j > i) s3 += c_l[j - i] * hv;
    }
    float h0 = (lane == 0) ? 1.f : s0;
    h_g[d * 256 + lane]       = h0;
    h_g[d * 256 + lane + 64]  = s1;
    h_g[d * 256 + lane + 128] = s2;
    h_g[d * 256 + lane + 192] = s3;
    h_l[lane] = h0; h_l[lane + 64] = s1; h_l[lane + 128] = s2; h_l[lane + 192] = s3;
    __syncthreads();
    float bv = bias[d];
    float S[4] = {0.f, 0.f, 0.f, 0.f};
    for (int m = 0; m < 256; ++m) {
        float hm = h_l[m];
#pragma unroll
        for (int k = 0; k < 4; ++k)
            if (m <= lane + 64 * k) S[k] += hm;
    }
#pragma unroll
    for (int k = 0; k < 4; ++k)
        Hb[d * 256 + lane + 64 * k] = bv * S[k];
}

// ---------------- k_gemm: Araw = Yt_d x Toep_d via MFMA ----------------
// grid 512: d = idx&31, bt = (idx>>5)&7, ks = idx>>8 (K split in half).
// block 256 thr / 4 waves; wave w: 64 b x 64 i = 4x4 tiles of 16x16x32.
// Depth-2 register prefetch, no LDS, no barriers.
__global__ __launch_bounds__(256, 2) void k_gemm(const ushort* __restrict__ Yt,
                                                 const ushort* __restrict__ Bf,
                                                 float* __restrict__ tmp) {
    int idx = blockIdx.x;
    int d = idx & 31, bt = (idx >> 5) & 7, ks = idx >> 8;
    int tid = threadIdx.x, w = tid >> 6, lane = tid & 63;
    int m = lane & 15, quad = lane >> 4;
    int b0 = bt * 64;
    int kt0 = ks * 32;

    const ushort* Ap = Yt + (size_t)(d * 512 + b0 + m) * L_SZ + quad * 8;
    const ushort* Bp = Bf + ((size_t)((d * 64) * 16 + w * 4) * 64 + lane) * 8;

    f32x4v acc[4][4];
#pragma unroll
    for (int mt = 0; mt < 4; ++mt)
#pragma unroll
        for (int nt = 0; nt < 4; ++nt) acc[mt][nt] = (f32x4v){0.f, 0.f, 0.f, 0.f};

    frag_ab a0[4], a1[4], bb0[4], bb1[4];
#define LOAD_A(dst, kt)  { _Pragma("unroll") for (int mt = 0; mt < 4; ++mt) \
        dst[mt] = *(const frag_ab*)(Ap + mt * 16 * L_SZ + (kt0 + (kt)) * 32); }
#define LOAD_B(dst, kt)  { _Pragma("unroll") for (int nt = 0; nt < 4; ++nt) \
        dst[nt] = *(const frag_ab*)(Bp + (size_t)((kt0 + (kt)) * 16 + nt) * 512); }
#define MFMA_ALL(af, bf) { _Pragma("unroll") for (int mt = 0; mt < 4; ++mt) \
        _Pragma("unroll") for (int nt = 0; nt < 4; ++nt) \
        acc[mt][nt] = __builtin_amdgcn_mfma_f32_16x16x32_bf16(af[mt], bf[nt], acc[mt][nt], 0, 0, 0); }

    LOAD_A(a0, 0); LOAD_B(bb0, 0);
    LOAD_A(a1, 1); LOAD_B(bb1, 1);
#pragma unroll 1
    for (int kt = 0; kt < 32; kt += 2) {
        MFMA_ALL(a0, bb0);
        if (kt + 2 < 32) { LOAD_A(a0, kt + 2); LOAD_B(bb0, kt + 2); }
        MFMA_ALL(a1, bb1);
        if (kt + 3 < 32) { LOAD_A(a1, kt + 3); LOAD_B(bb1, kt + 3); }
    }

    float* outp = tmp + ((size_t)ks * 32 + d) * (512 * 256);
#pragma unroll
    for (int mt = 0; mt < 4; ++mt)
#pragma unroll
        for (int nt = 0; nt < 4; ++nt) {
            int i = w * 64 + nt * 16 + m;
#pragma unroll
            for (int r = 0; r < 4; ++r) {
                int b = b0 + mt * 16 + quad * 4 + r;
                outp[(size_t)b * 256 + i] = acc[mt][nt][r];
            }
        }
#undef LOAD_A
#undef LOAD_B
#undef MFMA_ALL
}

// ---------------- k_conv: out = h (*) Araw + Hb, write [b][i][d] ----------------
// block = (b, d-half 16). Wave w handles i-groups 4w..4w+3 (uniform trip).
__global__ __launch_bounds__(256, 4) void k_conv(const float* __restrict__ tmp,
                                                 const float* __restrict__ h_g,
                                                 const float* __restrict__ Hb,
                                                 float* __restrict__ out) {
    __shared__ float A_l[16 * 324];   // 64 front zero-pad + 256, stride 324
    __shared__ float h_l[16 * 260];
    int b = blockIdx.x, d0 = blockIdx.y * 16;
    int tid = threadIdx.x;
    const float* t0p = tmp;
    const float* t1p = tmp + (size_t)32 * 512 * 256;
#pragma unroll
    for (int it = 0; it < 4; ++it) {
        int lin = tid + it * 256;              // 0..1023
        int rowid = lin >> 6, c4 = lin & 63;
        size_t off = ((size_t)(d0 + rowid) * 512 + b) * 256 + c4 * 4;
        float4 va = *(const float4*)(t0p + off);
        float4 vb = *(const float4*)(t1p + off);
        va.x += vb.x; va.y += vb.y; va.z += vb.z; va.w += vb.w;
        *(float4*)&A_l[rowid * 324 + 64 + c4 * 4] = va;
        *(float4*)&h_l[rowid * 260 + c4 * 4] =
            *(const float4*)(h_g + (d0 + rowid) * 256 + c4 * 4);
    }
#pragma unroll
    for (int it = 0; it < 4; ++it) {           // zero front pad
        int lin = tid + it * 256;              // 0..1023 = 16 rows x 64
        int rowid = lin >> 6, j = lin & 63;
        A_l[rowid * 324 + j] = 0.f;
    }
    __syncthreads();

    int dd = tid & 15, w = tid >> 6;
    int ig = w * 4 + ((tid >> 4) & 3);
    int i0 = ig * 16;
    float acc[16];
#pragma unroll
    for (int ii = 0; ii < 16; ++ii) acc[ii] = 0.f;
    float w24[24];
#pragma unroll
    for (int j6 = 0; j6 < 6; ++j6)
        *(float4*)&w24[j6 * 4] = *(float4*)&A_l[dd * 324 + i0 + 56 + j6 * 4];

    int P = (w + 1) * 8;                       // wave-uniform phase count
#pragma unroll 1
    for (int p = 0; p < P; ++p) {
        float4 h0 = *(float4*)&h_l[dd * 260 + p * 8];
        float4 h1 = *(float4*)&h_l[dd * 260 + p * 8 + 4];
        float hv[8] = {h0.x, h0.y, h0.z, h0.w, h1.x, h1.y, h1.z, h1.w};
#pragma unroll
        for (int q = 0; q < 8; ++q)
#pragma unroll
            for (int ii = 0; ii < 16; ++ii)
                acc[ii] += hv[q] * w24[ii + 8 - q];
#pragma unroll
        for (int j = 23; j >= 8; --j) w24[j] = w24[j - 8];
        if (p + 1 < P) {
            int nb = dd * 324 + i0 + 48 - p * 8;
            *(float4*)&w24[0] = *(float4*)&A_l[nb];
            *(float4*)&w24[4] = *(float4*)&A_l[nb + 4];
        }
    }
#pragma unroll
    for (int ii = 0; ii < 16; ++ii) {
        int i = i0 + ii;
        out[((size_t)b * 256 + i) * D_SZ + d0 + dd] = acc[ii] + Hb[(d0 + dd) * 256 + i];
    }
}

extern "C" void kernel_launch(void* const* d_in, const int* in_sizes, int n_in,
                              void* d_out, int out_size, void* d_ws, size_t ws_size,
                              hipStream_t stream) {
    const float* y_c  = (const float*)d_in[0];   // [512][2048][32]
    const float* W    = (const float*)d_in[1];   // [2048][32]
    const float* bias = (const float*)d_in[2];   // [32]
    float* out = (float*)d_out;                  // [512][256][32]

    char* ws = (char*)d_ws;
    ushort* Yt   = (ushort*)(ws);
    ushort* Bf   = (ushort*)(ws + 67108864);
    float*  tmp  = (float*) (ws + 100663296);    // [2][32][512][256]
    float*  h_g  = (float*) (ws + 134217728);
    float*  Hb   = (float*) (ws + 134250496);

    k_trans<<<dim3(64, 32), 256, 0, stream>>>(y_c, Yt);
    k_bfrag<<<dim3(64, 32), 256, 0, stream>>>(W, Bf);
    k1_h   <<<32, 64, 0, stream>>>(W, bias, h_g, Hb);
    k_gemm <<<512, 256, 0, stream>>>(Yt, Bf, tmp);
    k_conv <<<dim3(512, 2), 256, 0, stream>>>(tmp, h_g, Hb, out);
}

// Round 3
// 355.904 us; speedup vs baseline: 1.5082x; 1.0309x over previous
//
#include <hip/hip_runtime.h>

// Autoregressive linear model via LTI decomposition + bf16 MFMA:
//   Araw[b,i,d] = sum_t y[b,t,d] * W[t-i,d]          (k_gemm: 32 per-d GEMMs, MFMA)
//   h_d: impulse response of out_i = A_i + sum c_m out_{i-m}, c_m = W[2048-m]
//   out[b,i,d]  = sum_{m<=i} h_d[m]*Araw[b,i-m,d] + bias_d * cumsum(h_d)[i]
//
// R3: A is pre-permuted into MFMA fragment order by k_trans so every k_gemm
// load is a contiguous 1KB wave-load (fixes 4KB-stride gather storm of R2).
// K-split 4 -> grid 1024, 3 blocks/CU.
//
// ws layout (bytes):
//   Af  [32][8][64][4][64][8] bf16 @ 0          (67,108,864)  A fragments
//   Bf  [32][64][16][64][8] bf16  @ 67108864    (33,554,432)  B fragments
//   tmp [4][32][512][256] f32     @ 100663296   (67,108,864)  k-split partials
//   h_g [32][256] f32             @ 167772160   (32,768)
//   Hb  [32][256] f32             @ 167804928   (32,768)
// total ~160.1 MiB (ws is 512 MiB)

#define L_SZ   2048
#define D_SZ   32
#define NI_SZ  256

using frag_ab = __attribute__((ext_vector_type(8))) short;   // 8 bf16
using f32x4v  = __attribute__((ext_vector_type(4))) float;

__device__ inline ushort f2bf(float x) {
    uint32_t u = __float_as_uint(x);
    return (ushort)((u + 0x7fffu + ((u >> 16) & 1u)) >> 16);   // RTNE
}

// ---------------- k_trans: Y[b][t][d] f32 -> Af fragment blobs ----------------
// block = 16 b x 64 t (all 32 d). Grid (32 bq, 32 tq). bt = bq>>2, mt = bq&3.
// LDS: 512 rows (row = d*16 + bb) x 8 chunks of 16B (8 bf16 along t),
// chunk stored at slot = c ^ key(row), key = (row ^ (row>>3)) & 7.
// Read side (phase 2): lanes vary m=row&15 -> 2-way bank aliasing only (free).
__global__ __launch_bounds__(256) void k_trans(const float* __restrict__ Y,
                                               ushort* __restrict__ Af) {
    __shared__ ushort sm[512 * 64];   // 64 KB
    int bq = blockIdx.x, tq = blockIdx.y;
    int b0 = bq * 16, t0 = tq * 64;
    int tid = threadIdx.x;
    int dq = tid & 7, tt = (tid >> 3) & 7, wv = tid >> 6;
    // phase 1: coalesced f32 reads (1KB per wave-inst), bf16 convert, LDS scatter
#pragma unroll
    for (int bi = 0; bi < 4; ++bi) {
        int bb = wv * 4 + bi;
#pragma unroll
        for (int tg = 0; tg < 8; ++tg) {
            int t = tg * 8 + tt;
            float4 v = *(const float4*)(Y + ((size_t)(b0 + bb) * L_SZ + t0 + t) * D_SZ + dq * 4);
            ushort s[4] = {f2bf(v.x), f2bf(v.y), f2bf(v.z), f2bf(v.w)};
#pragma unroll
            for (int c = 0; c < 4; ++c) {
                int d = dq * 4 + c;
                int row = d * 16 + bb;
                int key = (row ^ (row >> 3)) & 7;
                sm[row * 64 + ((tg ^ key) * 8) + (t & 7)] = s[c];
            }
        }
    }
    __syncthreads();
    // phase 2: b128 LDS reads -> contiguous 1KB fragment stores
    int lane = tid & 63;
    int m = lane & 15, quad = lane >> 4;
    int bt = bq >> 2, mt = bq & 3;
#pragma unroll
    for (int j = 0; j < 16; ++j) {
        int fi = wv * 16 + j;
        int d = fi >> 1, ktl = fi & 1;
        int row = d * 16 + m;
        int key = (row ^ (row >> 3)) & 7;
        int cn = ktl * 4 + quad;
        uint4 u = *(uint4*)&sm[row * 64 + ((cn ^ key) * 8)];
        int ktg = tq * 2 + ktl;
        size_t off = ((((size_t)(d * 8 + bt) * 64 + ktg) * 4 + mt) * 64 + lane) * 8;
        *(uint4*)(Af + off) = u;
    }
}

// ---------------- k_bfrag: Toeplitz B in MFMA-fragment order ----------------
// Bf[d][kt][nt][lane][8]: lane l: n=l&15, quad=l>>4; j: k=kt*32+quad*8+j,
// i=nt*16+n, val = (0<=k-i<2048) ? W[(k-i)*32+d] : 0.
__global__ __launch_bounds__(256) void k_bfrag(const float* __restrict__ W,
                                               ushort* __restrict__ Bf) {
    int kt = blockIdx.x, d = blockIdx.y;
    int tid = threadIdx.x;
#pragma unroll
    for (int it = 0; it < 4; ++it) {
        int lin = tid + it * 256;          // 0..1023
        int lane = lin & 63, nt = lin >> 6;
        int n = lane & 15, quad = lane >> 4;
        int i = nt * 16 + n;
        ushort s[8];
#pragma unroll
        for (int j = 0; j < 8; ++j) {
            int k = kt * 32 + quad * 8 + j;
            int t = k - i;
            float v = (t >= 0 && t < L_SZ) ? W[t * D_SZ + d] : 0.f;
            s[j] = f2bf(v);
        }
        uint4 u;
        u.x = (uint)s[0] | ((uint)s[1] << 16);
        u.y = (uint)s[2] | ((uint)s[3] << 16);
        u.z = (uint)s[4] | ((uint)s[5] << 16);
        u.w = (uint)s[6] | ((uint)s[7] << 16);
        *(uint4*)(Bf + ((size_t)((d * 64 + kt) * 16 + nt) * 64 + lane) * 8) = u;
    }
}

// ---------------- k1: impulse response h + Hb = bias*cumsum(h) ----------------
__global__ __launch_bounds__(64) void k1_h(const float* __restrict__ W,
                                           const float* __restrict__ bias,
                                           float* __restrict__ h_g,
                                           float* __restrict__ Hb) {
    int d = blockIdx.x;
    int lane = threadIdx.x;
    __shared__ float c_l[256];
    __shared__ float h_l[256];
#pragma unroll
    for (int k = 0; k < 4; ++k) {
        int m = lane + 64 * k;
        c_l[m] = (m >= 1) ? W[(L_SZ - m) * D_SZ + d] : 0.f;
    }
    __syncthreads();
    float s0 = 0.f, s1 = 0.f, s2 = 0.f, s3 = 0.f;
    for (int i = 0; i < 256; ++i) {
        int slot = i >> 6;
        float v = (slot == 0) ? s0 : (slot == 1) ? s1 : (slot == 2) ? s2 : s3;
        float hv = (i == 0) ? 1.f : __shfl(v, i & 63, 64);
        int j;
        j = lane;        if (j > i) s0 += c_l[j - i] * hv;
        j = lane + 64;   if (j > i) s1 += c_l[j - i] * hv;
        j = lane + 128;  if (j > i) s2 += c_l[j - i] * hv;
        j = lane + 192;  if (j > i) s3 += c_l[j - i] * hv;
    }
    float h0 = (lane == 0) ? 1.f : s0;
    h_g[d * 256 + lane]       = h0;
    h_g[d * 256 + lane + 64]  = s1;
    h_g[d * 256 + lane + 128] = s2;
    h_g[d * 256 + lane + 192] = s3;
    h_l[lane] = h0; h_l[lane + 64] = s1; h_l[lane + 128] = s2; h_l[lane + 192] = s3;
    __syncthreads();
    float bv = bias[d];
    float S[4] = {0.f, 0.f, 0.f, 0.f};
    for (int m = 0; m < 256; ++m) {
        float hm = h_l[m];
#pragma unroll
        for (int k = 0; k < 4; ++k)
            if (m <= lane + 64 * k) S[k] += hm;
    }
#pragma unroll
    for (int k = 0; k < 4; ++k)
        Hb[d * 256 + lane + 64 * k] = bv * S[k];
}

// ---------------- k_gemm: Araw = A_frags x B_frags via MFMA ----------------
// grid 1024: d = idx&31, bt = (idx>>5)&7, ks = idx>>8 (K split in 4).
// All loads are contiguous 1KB wave-loads, sequential in kt.
__global__ __launch_bounds__(256, 3) void k_gemm(const ushort* __restrict__ Af,
                                                 const ushort* __restrict__ Bf,
                                                 float* __restrict__ tmp) {
    int idx = blockIdx.x;
    int d = idx & 31, bt = (idx >> 5) & 7, ks = idx >> 8;   // ks 0..3
    int tid = threadIdx.x, w = tid >> 6, lane = tid & 63;
    int m = lane & 15, quad = lane >> 4;

    const ushort* Ap = Af + (((size_t)(d * 8 + bt) * 64 + ks * 16) * 4) * 512 + lane * 8;
    const ushort* Bp = Bf + ((size_t)((d * 64 + ks * 16) * 16) + w * 4) * 512 + lane * 8;

    f32x4v acc[4][4];
#pragma unroll
    for (int mt = 0; mt < 4; ++mt)
#pragma unroll
        for (int nt = 0; nt < 4; ++nt) acc[mt][nt] = (f32x4v){0.f, 0.f, 0.f, 0.f};

    frag_ab a0[4], a1[4], bb0[4], bb1[4];
#define LOAD_A(dst, ktl)  { _Pragma("unroll") for (int mt = 0; mt < 4; ++mt) \
        dst[mt] = *(const frag_ab*)(Ap + (size_t)((ktl) * 4 + mt) * 512); }
#define LOAD_B(dst, ktl)  { _Pragma("unroll") for (int nt = 0; nt < 4; ++nt) \
        dst[nt] = *(const frag_ab*)(Bp + (size_t)((ktl) * 16 + nt) * 512); }
#define MFMA_ALL(af, bf) { _Pragma("unroll") for (int mt = 0; mt < 4; ++mt) \
        _Pragma("unroll") for (int nt = 0; nt < 4; ++nt) \
        acc[mt][nt] = __builtin_amdgcn_mfma_f32_16x16x32_bf16(af[mt], bf[nt], acc[mt][nt], 0, 0, 0); }

    LOAD_A(a0, 0); LOAD_B(bb0, 0);
    LOAD_A(a1, 1); LOAD_B(bb1, 1);
#pragma unroll 1
    for (int ktl = 0; ktl < 16; ktl += 2) {
        MFMA_ALL(a0, bb0);
        if (ktl + 2 < 16) { LOAD_A(a0, ktl + 2); LOAD_B(bb0, ktl + 2); }
        MFMA_ALL(a1, bb1);
        if (ktl + 3 < 16) { LOAD_A(a1, ktl + 3); LOAD_B(bb1, ktl + 3); }
    }

    float* outp = tmp + ((size_t)ks * 32 + d) * (512 * 256);
#pragma unroll
    for (int mt = 0; mt < 4; ++mt)
#pragma unroll
        for (int nt = 0; nt < 4; ++nt) {
            int i = w * 64 + nt * 16 + m;
#pragma unroll
            for (int r = 0; r < 4; ++r) {
                int b = bt * 64 + mt * 16 + quad * 4 + r;
                outp[(size_t)b * 256 + i] = acc[mt][nt][r];
            }
        }
#undef LOAD_A
#undef LOAD_B
#undef MFMA_ALL
}

// ---------------- k_conv: out = h (*) Araw + Hb, write [b][i][d] ----------------
// block = (b, d-half 16). Wave w handles i-groups 4w..4w+3 (uniform trip).
__global__ __launch_bounds__(256, 4) void k_conv(const float* __restrict__ tmp,
                                                 const float* __restrict__ h_g,
                                                 const float* __restrict__ Hb,
                                                 float* __restrict__ out) {
    __shared__ float A_l[16 * 324];   // 64 front zero-pad + 256, stride 324
    __shared__ float h_l[16 * 260];
    int b = blockIdx.x, d0 = blockIdx.y * 16;
    int tid = threadIdx.x;
    const size_t kstr = (size_t)32 * 512 * 256;
#pragma unroll
    for (int it = 0; it < 4; ++it) {
        int lin = tid + it * 256;              // 0..1023
        int rowid = lin >> 6, c4 = lin & 63;
        size_t off = ((size_t)(d0 + rowid) * 512 + b) * 256 + c4 * 4;
        float4 va = *(const float4*)(tmp + off);
#pragma unroll
        for (int ks = 1; ks < 4; ++ks) {
            float4 vb = *(const float4*)(tmp + ks * kstr + off);
            va.x += vb.x; va.y += vb.y; va.z += vb.z; va.w += vb.w;
        }
        *(float4*)&A_l[rowid * 324 + 64 + c4 * 4] = va;
        *(float4*)&h_l[rowid * 260 + c4 * 4] =
            *(const float4*)(h_g + (d0 + rowid) * 256 + c4 * 4);
    }
#pragma unroll
    for (int it = 0; it < 4; ++it) {           // zero front pad
        int lin = tid + it * 256;              // 0..1023 = 16 rows x 64
        int rowid = lin >> 6, j = lin & 63;
        A_l[rowid * 324 + j] = 0.f;
    }
    __syncthreads();

    int dd = tid & 15, w = tid >> 6;
    int ig = w * 4 + ((tid >> 4) & 3);
    int i0 = ig * 16;
    float acc[16];
#pragma unroll
    for (int ii = 0; ii < 16; ++ii) acc[ii] = 0.f;
    float w24[24];
#pragma unroll
    for (int j6 = 0; j6 < 6; ++j6)
        *(float4*)&w24[j6 * 4] = *(float4*)&A_l[dd * 324 + i0 + 56 + j6 * 4];

    int P = (w + 1) * 8;                       // wave-uniform phase count
#pragma unroll 1
    for (int p = 0; p < P; ++p) {
        float4 h0 = *(float4*)&h_l[dd * 260 + p * 8];
        float4 h1 = *(float4*)&h_l[dd * 260 + p * 8 + 4];
        float hv[8] = {h0.x, h0.y, h0.z, h0.w, h1.x, h1.y, h1.z, h1.w};
#pragma unroll
        for (int q = 0; q < 8; ++q)
#pragma unroll
            for (int ii = 0; ii < 16; ++ii)
                acc[ii] += hv[q] * w24[ii + 8 - q];
#pragma unroll
        for (int j = 23; j >= 8; --j) w24[j] = w24[j - 8];
        if (p + 1 < P) {
            int nb = dd * 324 + i0 + 48 - p * 8;
            *(float4*)&w24[0] = *(float4*)&A_l[nb];
            *(float4*)&w24[4] = *(float4*)&A_l[nb + 4];
        }
    }
#pragma unroll
    for (int ii = 0; ii < 16; ++ii) {
        int i = i0 + ii;
        out[((size_t)b * 256 + i) * D_SZ + d0 + dd] = acc[ii] + Hb[(d0 + dd) * 256 + i];
    }
}

extern "C" void kernel_launch(void* const* d_in, const int* in_sizes, int n_in,
                              void* d_out, int out_size, void* d_ws, size_t ws_size,
                              hipStream_t stream) {
    const float* y_c  = (const float*)d_in[0];   // [512][2048][32]
    const float* W    = (const float*)d_in[1];   // [2048][32]
    const float* bias = (const float*)d_in[2];   // [32]
    float* out = (float*)d_out;                  // [512][256][32]

    char* ws = (char*)d_ws;
    ushort* Af   = (ushort*)(ws);
    ushort* Bf   = (ushort*)(ws + 67108864);
    float*  tmp  = (float*) (ws + 100663296);    // [4][32][512][256]
    float*  h_g  = (float*) (ws + 167772160);
    float*  Hb   = (float*) (ws + 167804928);

    k_trans<<<dim3(32, 32), 256, 0, stream>>>(y_c, Af);
    k_bfrag<<<dim3(64, 32), 256, 0, stream>>>(W, Bf);
    k1_h   <<<32, 64, 0, stream>>>(W, bias, h_g, Hb);
    k_gemm <<<1024, 256, 0, stream>>>(Af, Bf, tmp);
    k_conv <<<dim3(512, 2), 256, 0, stream>>>(tmp, h_g, Hb, out);
}

// Round 4
// 339.194 us; speedup vs baseline: 1.5825x; 1.0493x over previous
//
#include <hip/hip_runtime.h>

// Autoregressive linear model via LTI decomposition + bf16 MFMA:
//   Araw[b,i,d] = sum_t y[b,t,d] * W[t-i,d]          (k_gemm: 32 per-d GEMMs, MFMA)
//   h_d: impulse response of out_i = A_i + sum c_m out_{i-m}, c_m = W[2048-m]
//   out[b,i,d]  = sum_{m<=i} h_d[m]*Araw[b,i-m,d] + bias_d * cumsum(h_d)[i]
//
// R4: k_trans uses register-transpose + b128 swizzled LDS writes (R3 had a
// 16-way-conflicted scalar b16 scatter); k_bfrag reads a pre-transposed
// Wt[d][t] staged in LDS (R3 gathered W at 128B stride). k_gemm/k_conv
// unchanged from R3 for attribution.
//
// ws layout (bytes):
//   Af  [32][8][64][4][64][8] bf16 @ 0          (67,108,864)  A fragments
//   Bf  [32][64][16][64][8] bf16  @ 67108864    (33,554,432)  B fragments
//   tmp [4][32][512][256] f32     @ 100663296   (67,108,864)  k-split partials
//   h_g [32][256] f32             @ 167772160   (32,768)
//   Hb  [32][256] f32             @ 167804928   (32,768)
//   Wt  [32][2048] f32            @ 167837696   (262,144)
// total ~160.4 MiB (ws is 512 MiB)

#define L_SZ   2048
#define D_SZ   32
#define NI_SZ  256

using frag_ab = __attribute__((ext_vector_type(8))) short;   // 8 bf16
using f32x4v  = __attribute__((ext_vector_type(4))) float;

__device__ inline ushort f2bf(float x) {
    uint32_t u = __float_as_uint(x);
    return (ushort)((u + 0x7fffu + ((u >> 16) & 1u)) >> 16);   // RTNE
}

// ---------------- k_wt: W[t][d] -> Wt[d][t] (256 KiB, tiny) ----------------
__global__ __launch_bounds__(256) void k_wt(const float* __restrict__ W,
                                            float* __restrict__ Wt) {
    __shared__ float sm[32 * 132];
    int t0 = blockIdx.x * 128;
    int tid = threadIdx.x;
#pragma unroll
    for (int it = 0; it < 4; ++it) {
        int lin = tid + it * 256;          // 0..1023 = 8 dq x 128 tt
        int dq = lin & 7, tt = lin >> 3;
        float4 v = *(const float4*)(W + (size_t)(t0 + tt) * 32 + dq * 4);
        sm[(dq * 4 + 0) * 132 + tt] = v.x;
        sm[(dq * 4 + 1) * 132 + tt] = v.y;
        sm[(dq * 4 + 2) * 132 + tt] = v.z;
        sm[(dq * 4 + 3) * 132 + tt] = v.w;
    }
    __syncthreads();
#pragma unroll
    for (int it = 0; it < 4; ++it) {
        int lin = tid + it * 256;          // 32 tc x 32 d
        int tc = lin & 31, d = lin >> 5;
        float4 v = *(float4*)&sm[d * 132 + tc * 4];   // 528B row stride: 16B aligned
        *(float4*)(Wt + (size_t)d * 2048 + t0 + tc * 4) = v;
    }
}

// ---------------- k_trans: Y[b][t][d] f32 -> Af fragment blobs ----------------
// block = 16 b x 64 t (all 32 d). Grid (32 bq, 32 tq). bt = bq>>2, mt = bq&3.
// Register-transpose: each work item loads 8 float4 along t, packs 8 bf16 per
// d into ONE b128 LDS write. LDS: row = d*16 + bb, 8 chunks of 16B, chunk c
// stored at slot c ^ key, key = (row ^ (row>>3)) & 7. Both the b128 write and
// b128 read patterns hit each 4-bank group with 8 lanes at distinct addrs =
// the 8-phase b128 minimum (no excess conflicts).
__global__ __launch_bounds__(256) void k_trans(const float* __restrict__ Y,
                                               ushort* __restrict__ Af) {
    __shared__ ushort sm[512 * 64];   // 64 KB
    int bq = blockIdx.x, tq = blockIdx.y;
    int b0 = bq * 16, t0 = tq * 64;
    int tid = threadIdx.x;
    // phase 1: 1024 work items = 8 dq x 16 bb x 8 tg; 8 float4 loads each
#pragma unroll
    for (int it = 0; it < 4; ++it) {
        int g = tid + it * 256;
        int dq = g & 7, bb = (g >> 3) & 15, tg = g >> 7;
        float4 v[8];
#pragma unroll
        for (int q = 0; q < 8; ++q)
            v[q] = *(const float4*)(Y + ((size_t)(b0 + bb) * L_SZ + t0 + tg * 8 + q) * D_SZ + dq * 4);
#pragma unroll
        for (int c = 0; c < 4; ++c) {
            int row = (dq * 4 + c) * 16 + bb;
            int key = (row ^ (row >> 3)) & 7;
            uint4 u;
            u.x = (uint)f2bf((&v[0].x)[c]) | ((uint)f2bf((&v[1].x)[c]) << 16);
            u.y = (uint)f2bf((&v[2].x)[c]) | ((uint)f2bf((&v[3].x)[c]) << 16);
            u.z = (uint)f2bf((&v[4].x)[c]) | ((uint)f2bf((&v[5].x)[c]) << 16);
            u.w = (uint)f2bf((&v[6].x)[c]) | ((uint)f2bf((&v[7].x)[c]) << 16);
            *(uint4*)&sm[row * 64 + ((tg ^ key) * 8)] = u;
        }
    }
    __syncthreads();
    // phase 2: b128 LDS reads -> contiguous 1KB fragment stores
    int wv = tid >> 6, lane = tid & 63;
    int m = lane & 15, quad = lane >> 4;
    int bt = bq >> 2, mt = bq & 3;
#pragma unroll
    for (int j = 0; j < 16; ++j) {
        int fi = wv * 16 + j;              // 0..63 = 32 d x 2 ktl
        int d = fi >> 1, ktl = fi & 1;
        int row = d * 16 + m;
        int key = (row ^ (row >> 3)) & 7;
        int cn = ktl * 4 + quad;
        uint4 u = *(uint4*)&sm[row * 64 + ((cn ^ key) * 8)];
        int ktg = tq * 2 + ktl;
        size_t off = ((((size_t)(d * 8 + bt) * 64 + ktg) * 4 + mt) * 64 + lane) * 8;
        *(uint4*)(Af + off) = u;
    }
}

// ---------------- k_bfrag: Toeplitz B fragments from LDS-staged Wt ----------
// Bf[d][kt][nt][lane][8]: lane l: n=l&15, quad=l>>4; j: t = kt*32+quad*8+j
// - nt*16 - n. Window t in [kt*32-255, kt*32+31] staged (zero-clamped).
__global__ __launch_bounds__(256) void k_bfrag(const float* __restrict__ Wt,
                                               ushort* __restrict__ Bf) {
    __shared__ float wl[320];
    int kt = blockIdx.x, d = blockIdx.y;
    int tid = threadIdx.x;
    int lo = kt * 32 - 255;
    for (int s = tid; s < 320; s += 256) {
        int t = lo + s;
        wl[s] = (t >= 0 && t < L_SZ) ? Wt[(size_t)d * 2048 + t] : 0.f;
    }
    __syncthreads();
#pragma unroll
    for (int it = 0; it < 4; ++it) {
        int lin = tid + it * 256;          // 0..1023
        int lane = lin & 63, nt = lin >> 6;
        int n = lane & 15, quad = lane >> 4;
        int base = quad * 8 + 255 - nt * 16 - n;   // wl index of j=0
        ushort s[8];
#pragma unroll
        for (int j = 0; j < 8; ++j) s[j] = f2bf(wl[base + j]);
        uint4 u;
        u.x = (uint)s[0] | ((uint)s[1] << 16);
        u.y = (uint)s[2] | ((uint)s[3] << 16);
        u.z = (uint)s[4] | ((uint)s[5] << 16);
        u.w = (uint)s[6] | ((uint)s[7] << 16);
        *(uint4*)(Bf + ((size_t)((d * 64 + kt) * 16 + nt) * 64 + lane) * 8) = u;
    }
}

// ---------------- k1: impulse response h + Hb = bias*cumsum(h) ----------------
__global__ __launch_bounds__(64) void k1_h(const float* __restrict__ W,
                                           const float* __restrict__ bias,
                                           float* __restrict__ h_g,
                                           float* __restrict__ Hb) {
    int d = blockIdx.x;
    int lane = threadIdx.x;
    __shared__ float c_l[256];
    __shared__ float h_l[256];
#pragma unroll
    for (int k = 0; k < 4; ++k) {
        int m = lane + 64 * k;
        c_l[m] = (m >= 1) ? W[(L_SZ - m) * D_SZ + d] : 0.f;
    }
    __syncthreads();
    float s0 = 0.f, s1 = 0.f, s2 = 0.f, s3 = 0.f;
    for (int i = 0; i < 256; ++i) {
        int slot = i >> 6;
        float v = (slot == 0) ? s0 : (slot == 1) ? s1 : (slot == 2) ? s2 : s3;
        float hv = (i == 0) ? 1.f : __shfl(v, i & 63, 64);
        int j;
        j = lane;        if (j > i) s0 += c_l[j - i] * hv;
        j = lane + 64;   if (j > i) s1 += c_l[j - i] * hv;
        j = lane + 128;  if (j > i) s2 += c_l[j - i] * hv;
        j = lane + 192;  if (j > i) s3 += c_l[j - i] * hv;
    }
    float h0 = (lane == 0) ? 1.f : s0;
    h_g[d * 256 + lane]       = h0;
    h_g[d * 256 + lane + 64]  = s1;
    h_g[d * 256 + lane + 128] = s2;
    h_g[d * 256 + lane + 192] = s3;
    h_l[lane] = h0; h_l[lane + 64] = s1; h_l[lane + 128] = s2; h_l[lane + 192] = s3;
    __syncthreads();
    float bv = bias[d];
    float S[4] = {0.f, 0.f, 0.f, 0.f};
    for (int m = 0; m < 256; ++m) {
        float hm = h_l[m];
#pragma unroll
        for (int k = 0; k < 4; ++k)
            if (m <= lane + 64 * k) S[k] += hm;
    }
#pragma unroll
    for (int k = 0; k < 4; ++k)
        Hb[d * 256 + lane + 64 * k] = bv * S[k];
}

// ---------------- k_gemm: Araw = A_frags x B_frags via MFMA (unchanged) ------
__global__ __launch_bounds__(256, 3) void k_gemm(const ushort* __restrict__ Af,
                                                 const ushort* __restrict__ Bf,
                                                 float* __restrict__ tmp) {
    int idx = blockIdx.x;
    int d = idx & 31, bt = (idx >> 5) & 7, ks = idx >> 8;   // ks 0..3
    int tid = threadIdx.x, w = tid >> 6, lane = tid & 63;
    int m = lane & 15, quad = lane >> 4;

    const ushort* Ap = Af + (((size_t)(d * 8 + bt) * 64 + ks * 16) * 4) * 512 + lane * 8;
    const ushort* Bp = Bf + ((size_t)((d * 64 + ks * 16) * 16) + w * 4) * 512 + lane * 8;

    f32x4v acc[4][4];
#pragma unroll
    for (int mt = 0; mt < 4; ++mt)
#pragma unroll
        for (int nt = 0; nt < 4; ++nt) acc[mt][nt] = (f32x4v){0.f, 0.f, 0.f, 0.f};

    frag_ab a0[4], a1[4], bb0[4], bb1[4];
#define LOAD_A(dst, ktl)  { _Pragma("unroll") for (int mt = 0; mt < 4; ++mt) \
        dst[mt] = *(const frag_ab*)(Ap + (size_t)((ktl) * 4 + mt) * 512); }
#define LOAD_B(dst, ktl)  { _Pragma("unroll") for (int nt = 0; nt < 4; ++nt) \
        dst[nt] = *(const frag_ab*)(Bp + (size_t)((ktl) * 16 + nt) * 512); }
#define MFMA_ALL(af, bf) { _Pragma("unroll") for (int mt = 0; mt < 4; ++mt) \
        _Pragma("unroll") for (int nt = 0; nt < 4; ++nt) \
        acc[mt][nt] = __builtin_amdgcn_mfma_f32_16x16x32_bf16(af[mt], bf[nt], acc[mt][nt], 0, 0, 0); }

    LOAD_A(a0, 0); LOAD_B(bb0, 0);
    LOAD_A(a1, 1); LOAD_B(bb1, 1);
#pragma unroll 1
    for (int ktl = 0; ktl < 16; ktl += 2) {
        MFMA_ALL(a0, bb0);
        if (ktl + 2 < 16) { LOAD_A(a0, ktl + 2); LOAD_B(bb0, ktl + 2); }
        MFMA_ALL(a1, bb1);
        if (ktl + 3 < 16) { LOAD_A(a1, ktl + 3); LOAD_B(bb1, ktl + 3); }
    }

    float* outp = tmp + ((size_t)ks * 32 + d) * (512 * 256);
#pragma unroll
    for (int mt = 0; mt < 4; ++mt)
#pragma unroll
        for (int nt = 0; nt < 4; ++nt) {
            int i = w * 64 + nt * 16 + m;
#pragma unroll
            for (int r = 0; r < 4; ++r) {
                int b = bt * 64 + mt * 16 + quad * 4 + r;
                outp[(size_t)b * 256 + i] = acc[mt][nt][r];
            }
        }
#undef LOAD_A
#undef LOAD_B
#undef MFMA_ALL
}

// ---------------- k_conv: out = h (*) Araw + Hb (unchanged) ----------------
__global__ __launch_bounds__(256, 4) void k_conv(const float* __restrict__ tmp,
                                                 const float* __restrict__ h_g,
                                                 const float* __restrict__ Hb,
                                                 float* __restrict__ out) {
    __shared__ float A_l[16 * 324];   // 64 front zero-pad + 256, stride 324
    __shared__ float h_l[16 * 260];
    int b = blockIdx.x, d0 = blockIdx.y * 16;
    int tid = threadIdx.x;
    const size_t kstr = (size_t)32 * 512 * 256;
#pragma unroll
    for (int it = 0; it < 4; ++it) {
        int lin = tid + it * 256;              // 0..1023
        int rowid = lin >> 6, c4 = lin & 63;
        size_t off = ((size_t)(d0 + rowid) * 512 + b) * 256 + c4 * 4;
        float4 va = *(const float4*)(tmp + off);
#pragma unroll
        for (int ks = 1; ks < 4; ++ks) {
            float4 vb = *(const float4*)(tmp + ks * kstr + off);
            va.x += vb.x; va.y += vb.y; va.z += vb.z; va.w += vb.w;
        }
        *(float4*)&A_l[rowid * 324 + 64 + c4 * 4] = va;
        *(float4*)&h_l[rowid * 260 + c4 * 4] =
            *(const float4*)(h_g + (d0 + rowid) * 256 + c4 * 4);
    }
#pragma unroll
    for (int it = 0; it < 4; ++it) {           // zero front pad
        int lin = tid + it * 256;
        int rowid = lin >> 6, j = lin & 63;
        A_l[rowid * 324 + j] = 0.f;
    }
    __syncthreads();

    int dd = tid & 15, w = tid >> 6;
    int ig = w * 4 + ((tid >> 4) & 3);
    int i0 = ig * 16;
    float acc[16];
#pragma unroll
    for (int ii = 0; ii < 16; ++ii) acc[ii] = 0.f;
    float w24[24];
#pragma unroll
    for (int j6 = 0; j6 < 6; ++j6)
        *(float4*)&w24[j6 * 4] = *(float4*)&A_l[dd * 324 + i0 + 56 + j6 * 4];

    int P = (w + 1) * 8;                       // wave-uniform phase count
#pragma unroll 1
    for (int p = 0; p < P; ++p) {
        float4 h0 = *(float4*)&h_l[dd * 260 + p * 8];
        float4 h1 = *(float4*)&h_l[dd * 260 + p * 8 + 4];
        float hv[8] = {h0.x, h0.y, h0.z, h0.w, h1.x, h1.y, h1.z, h1.w};
#pragma unroll
        for (int q = 0; q < 8; ++q)
#pragma unroll
            for (int ii = 0; ii < 16; ++ii)
                acc[ii] += hv[q] * w24[ii + 8 - q];
#pragma unroll
        for (int j = 23; j >= 8; --j) w24[j] = w24[j - 8];
        if (p + 1 < P) {
            int nb = dd * 324 + i0 + 48 - p * 8;
            *(float4*)&w24[0] = *(float4*)&A_l[nb];
            *(float4*)&w24[4] = *(float4*)&A_l[nb + 4];
        }
    }
#pragma unroll
    for (int ii = 0; ii < 16; ++ii) {
        int i = i0 + ii;
        out[((size_t)b * 256 + i) * D_SZ + d0 + dd] = acc[ii] + Hb[(d0 + dd) * 256 + i];
    }
}

extern "C" void kernel_launch(void* const* d_in, const int* in_sizes, int n_in,
                              void* d_out, int out_size, void* d_ws, size_t ws_size,
                              hipStream_t stream) {
    const float* y_c  = (const float*)d_in[0];   // [512][2048][32]
    const float* W    = (const float*)d_in[1];   // [2048][32]
    const float* bias = (const float*)d_in[2];   // [32]
    float* out = (float*)d_out;                  // [512][256][32]

    char* ws = (char*)d_ws;
    ushort* Af   = (ushort*)(ws);
    ushort* Bf   = (ushort*)(ws + 67108864);
    float*  tmp  = (float*) (ws + 100663296);    // [4][32][512][256]
    float*  h_g  = (float*) (ws + 167772160);
    float*  Hb   = (float*) (ws + 167804928);
    float*  Wt   = (float*) (ws + 167837696);    // [32][2048]

    k_wt   <<<16, 256, 0, stream>>>(W, Wt);
    k_trans<<<dim3(32, 32), 256, 0, stream>>>(y_c, Af);
    k_bfrag<<<dim3(64, 32), 256, 0, stream>>>(Wt, Bf);
    k1_h   <<<32, 64, 0, stream>>>(W, bias, h_g, Hb);
    k_gemm <<<1024, 256, 0, stream>>>(Af, Bf, tmp);
    k_conv <<<dim3(512, 2), 256, 0, stream>>>(tmp, h_g, Hb, out);
}

// Round 5
// 331.300 us; speedup vs baseline: 1.6202x; 1.0238x over previous
//
#include <hip/hip_runtime.h>

// Autoregressive linear model via LTI decomposition + bf16 MFMA:
//   Araw[b,i,d] = sum_t y[b,t,d] * W[t-i,d]          (k_fused GEMM phase, MFMA)
//   h_d: impulse response of out_i = A_i + sum c_m out_{i-m}, c_m = W[2048-m]
//   out[b,i,d]  = sum_{m<=i} h_d[m]*Araw[b,i-m,d] + bias_d * cumsum(h_d)[i]
//
// R5: k_gemm + k_conv fused (no k-split, no tmp round trip: saves ~268 MB
// HBM). Block = (d, 32 b, 256 i, K=2048); XCD swizzle keeps all 16 same-d
// blocks on one XCD so Bf[d] (1 MiB) is L2-resident. MFMA acc -> LDS -> IIR
// conv in-block -> Og[d][b][i] (full-line writes); k_outT transposes to
// [b][i][d] with full-line writes on both sides.
//
// ws layout (bytes):
//   Af  [32][8][64][4][64][8] bf16 @ 0          (67,108,864)  A fragments
//   Bf  [32][64][16][64][8] bf16  @ 67108864    (33,554,432)  B fragments
//   Og  [32][512][256] f32        @ 100663296   (16,777,216)  pre-transpose out
//   h_g [32][256] f32             @ 117440512   (32,768)
//   Hb  [32][256] f32             @ 117473280   (32,768)
//   Wt  [32][2048] f32            @ 117506048   (262,144)
// total ~112.3 MiB (ws is 512 MiB)

#define L_SZ   2048
#define D_SZ   32
#define NI_SZ  256
#define ST_A   324     // A_l row stride (f32): 64 front zero-pad + 256 + 4

using frag_ab = __attribute__((ext_vector_type(8))) short;   // 8 bf16
using f32x4v  = __attribute__((ext_vector_type(4))) float;

__device__ inline ushort f2bf(float x) {
    uint32_t u = __float_as_uint(x);
    return (ushort)((u + 0x7fffu + ((u >> 16) & 1u)) >> 16);   // RTNE
}

// ---------------- k_wt: W[t][d] -> Wt[d][t] (256 KiB, tiny) ----------------
__global__ __launch_bounds__(256) void k_wt(const float* __restrict__ W,
                                            float* __restrict__ Wt) {
    __shared__ float sm[32 * 132];
    int t0 = blockIdx.x * 128;
    int tid = threadIdx.x;
#pragma unroll
    for (int it = 0; it < 4; ++it) {
        int lin = tid + it * 256;          // 0..1023 = 8 dq x 128 tt
        int dq = lin & 7, tt = lin >> 3;
        float4 v = *(const float4*)(W + (size_t)(t0 + tt) * 32 + dq * 4);
        sm[(dq * 4 + 0) * 132 + tt] = v.x;
        sm[(dq * 4 + 1) * 132 + tt] = v.y;
        sm[(dq * 4 + 2) * 132 + tt] = v.z;
        sm[(dq * 4 + 3) * 132 + tt] = v.w;
    }
    __syncthreads();
#pragma unroll
    for (int it = 0; it < 4; ++it) {
        int lin = tid + it * 256;          // 32 tc x 32 d
        int tc = lin & 31, d = lin >> 5;
        float4 v = *(float4*)&sm[d * 132 + tc * 4];
        *(float4*)(Wt + (size_t)d * 2048 + t0 + tc * 4) = v;
    }
}

// ---------------- k_trans: Y[b][t][d] f32 -> Af fragment blobs ----------------
// (unchanged from R4: register-transpose + b128 swizzled LDS, conflict-free)
__global__ __launch_bounds__(256) void k_trans(const float* __restrict__ Y,
                                               ushort* __restrict__ Af) {
    __shared__ ushort sm[512 * 64];   // 64 KB
    int bq = blockIdx.x, tq = blockIdx.y;
    int b0 = bq * 16, t0 = tq * 64;
    int tid = threadIdx.x;
#pragma unroll
    for (int it = 0; it < 4; ++it) {
        int g = tid + it * 256;
        int dq = g & 7, bb = (g >> 3) & 15, tg = g >> 7;
        float4 v[8];
#pragma unroll
        for (int q = 0; q < 8; ++q)
            v[q] = *(const float4*)(Y + ((size_t)(b0 + bb) * L_SZ + t0 + tg * 8 + q) * D_SZ + dq * 4);
#pragma unroll
        for (int c = 0; c < 4; ++c) {
            int row = (dq * 4 + c) * 16 + bb;
            int key = (row ^ (row >> 3)) & 7;
            uint4 u;
            u.x = (uint)f2bf((&v[0].x)[c]) | ((uint)f2bf((&v[1].x)[c]) << 16);
            u.y = (uint)f2bf((&v[2].x)[c]) | ((uint)f2bf((&v[3].x)[c]) << 16);
            u.z = (uint)f2bf((&v[4].x)[c]) | ((uint)f2bf((&v[5].x)[c]) << 16);
            u.w = (uint)f2bf((&v[6].x)[c]) | ((uint)f2bf((&v[7].x)[c]) << 16);
            *(uint4*)&sm[row * 64 + ((tg ^ key) * 8)] = u;
        }
    }
    __syncthreads();
    int wv = tid >> 6, lane = tid & 63;
    int m = lane & 15, quad = lane >> 4;
    int bt = bq >> 2, mt = bq & 3;
#pragma unroll
    for (int j = 0; j < 16; ++j) {
        int fi = wv * 16 + j;              // 0..63 = 32 d x 2 ktl
        int d = fi >> 1, ktl = fi & 1;
        int row = d * 16 + m;
        int key = (row ^ (row >> 3)) & 7;
        int cn = ktl * 4 + quad;
        uint4 u = *(uint4*)&sm[row * 64 + ((cn ^ key) * 8)];
        int ktg = tq * 2 + ktl;
        size_t off = ((((size_t)(d * 8 + bt) * 64 + ktg) * 4 + mt) * 64 + lane) * 8;
        *(uint4*)(Af + off) = u;
    }
}

// ---------------- k_bfrag: Toeplitz B fragments from LDS-staged Wt ----------
__global__ __launch_bounds__(256) void k_bfrag(const float* __restrict__ Wt,
                                               ushort* __restrict__ Bf) {
    __shared__ float wl[320];
    int kt = blockIdx.x, d = blockIdx.y;
    int tid = threadIdx.x;
    int lo = kt * 32 - 255;
    for (int s = tid; s < 320; s += 256) {
        int t = lo + s;
        wl[s] = (t >= 0 && t < L_SZ) ? Wt[(size_t)d * 2048 + t] : 0.f;
    }
    __syncthreads();
#pragma unroll
    for (int it = 0; it < 4; ++it) {
        int lin = tid + it * 256;          // 0..1023
        int lane = lin & 63, nt = lin >> 6;
        int n = lane & 15, quad = lane >> 4;
        int base = quad * 8 + 255 - nt * 16 - n;   // wl index of j=0
        ushort s[8];
#pragma unroll
        for (int j = 0; j < 8; ++j) s[j] = f2bf(wl[base + j]);
        uint4 u;
        u.x = (uint)s[0] | ((uint)s[1] << 16);
        u.y = (uint)s[2] | ((uint)s[3] << 16);
        u.z = (uint)s[4] | ((uint)s[5] << 16);
        u.w = (uint)s[6] | ((uint)s[7] << 16);
        *(uint4*)(Bf + ((size_t)((d * 64 + kt) * 16 + nt) * 64 + lane) * 8) = u;
    }
}

// ---------------- k1: impulse response h + Hb = bias*cumsum(h) ----------------
__global__ __launch_bounds__(64) void k1_h(const float* __restrict__ W,
                                           const float* __restrict__ bias,
                                           float* __restrict__ h_g,
                                           float* __restrict__ Hb) {
    int d = blockIdx.x;
    int lane = threadIdx.x;
    __shared__ float c_l[256];
    __shared__ float h_l[256];
#pragma unroll
    for (int k = 0; k < 4; ++k) {
        int m = lane + 64 * k;
        c_l[m] = (m >= 1) ? W[(L_SZ - m) * D_SZ + d] : 0.f;
    }
    __syncthreads();
    float s0 = 0.f, s1 = 0.f, s2 = 0.f, s3 = 0.f;
    for (int i = 0; i < 256; ++i) {
        int slot = i >> 6;
        float v = (slot == 0) ? s0 : (slot == 1) ? s1 : (slot == 2) ? s2 : s3;
        float hv = (i == 0) ? 1.f : __shfl(v, i & 63, 64);
        int j;
        j = lane;        if (j > i) s0 += c_l[j - i] * hv;
        j = lane + 64;   if (j > i) s1 += c_l[j - i] * hv;
        j = lane + 128;  if (j > i) s2 += c_l[j - i] * hv;
        j = lane + 192;  if (j > i) s3 += c_l[j - i] * hv;
    }
    float h0 = (lane == 0) ? 1.f : s0;
    h_g[d * 256 + lane]       = h0;
    h_g[d * 256 + lane + 64]  = s1;
    h_g[d * 256 + lane + 128] = s2;
    h_g[d * 256 + lane + 192] = s3;
    h_l[lane] = h0; h_l[lane + 64] = s1; h_l[lane + 128] = s2; h_l[lane + 192] = s3;
    __syncthreads();
    float bv = bias[d];
    float S[4] = {0.f, 0.f, 0.f, 0.f};
    for (int m = 0; m < 256; ++m) {
        float hm = h_l[m];
#pragma unroll
        for (int k = 0; k < 4; ++k)
            if (m <= lane + 64 * k) S[k] += hm;
    }
#pragma unroll
    for (int k = 0; k < 4; ++k)
        Hb[d * 256 + lane + 64 * k] = bv * S[k];
}

// ---------------- k_fused: GEMM (MFMA) + IIR conv, one block per (d, 32b) ---
// grid 512: d = (idx&7)*4 + ((idx>>3)&3)  [XCD-swizzle: same-d -> same XCD],
// bt2 = idx>>5 (0..15; 32 b's each). Wave w covers b 0..31 x i [w*64,w*64+64).
// GEMM: depth-4 register prefetch, full K=2048, no barriers. Acc -> LDS ->
// causal conv with h (front zero-pad masks both the triangular boundary and
// the wave-divergent trip counts) -> Og[d][b][i].
__global__ __launch_bounds__(256, 2) void k_fused(const ushort* __restrict__ Af,
                                                  const ushort* __restrict__ Bf,
                                                  const float* __restrict__ h_g,
                                                  const float* __restrict__ Hb,
                                                  float* __restrict__ Og) {
    __shared__ float A_l[32 * ST_A];   // 41.5 KB
    __shared__ float h_l[256];
    __shared__ float hb_l[256];
    int idx = blockIdx.x;
    int d   = (idx & 7) * 4 + ((idx >> 3) & 3);
    int bt2 = idx >> 5;                 // 0..15
    int bt  = bt2 >> 1, msel = (bt2 & 1) * 2;
    int tid = threadIdx.x, w = tid >> 6, lane = tid & 63;
    int m = lane & 15, quad = lane >> 4;

    // stage h/Hb + zero A_l front pad (independent of GEMM; no barrier yet)
    h_l[tid]  = h_g[d * 256 + tid];
    hb_l[tid] = Hb[d * 256 + tid];
    {
        int r = tid >> 3, c = (tid & 7) * 8;
#pragma unroll
        for (int k = 0; k < 8; ++k) A_l[r * ST_A + c + k] = 0.f;
    }

    const ushort* Ap = Af + ((size_t)(d * 8 + bt) * 256 + msel) * 512 + (size_t)lane * 8;
    const ushort* Bp = Bf + ((size_t)d * 1024 + w * 4) * 512 + (size_t)lane * 8;

    f32x4v acc[2][4];
#pragma unroll
    for (int mi = 0; mi < 2; ++mi)
#pragma unroll
        for (int nt = 0; nt < 4; ++nt) acc[mi][nt] = (f32x4v){0.f, 0.f, 0.f, 0.f};

    frag_ab a[4][2], bb[4][4];
#define LOADG(s, ktl) { _Pragma("unroll") for (int mi = 0; mi < 2; ++mi) \
        a[s][mi] = *(const frag_ab*)(Ap + (size_t)((ktl) * 4 + mi) * 512); \
    _Pragma("unroll") for (int nt = 0; nt < 4; ++nt) \
        bb[s][nt] = *(const frag_ab*)(Bp + (size_t)((ktl) * 16 + nt) * 512); }
#define MFMA_G(s) { _Pragma("unroll") for (int mi = 0; mi < 2; ++mi) \
        _Pragma("unroll") for (int nt = 0; nt < 4; ++nt) \
        acc[mi][nt] = __builtin_amdgcn_mfma_f32_16x16x32_bf16(a[s][mi], bb[s][nt], acc[mi][nt], 0, 0, 0); }

#pragma unroll
    for (int pf = 0; pf < 4; ++pf) LOADG(pf, pf);
#pragma unroll 1
    for (int kt4 = 0; kt4 < 15; ++kt4) {
#pragma unroll
        for (int s = 0; s < 4; ++s) {
            MFMA_G(s);
            LOADG(s, kt4 * 4 + s + 4);
        }
    }
#pragma unroll
    for (int s = 0; s < 4; ++s) MFMA_G(s);
#undef LOADG
#undef MFMA_G

    // acc -> LDS: b_local = mi*16+quad*4+r, i = w*64+nt*16+m  (2-way banks: free)
#pragma unroll
    for (int mi = 0; mi < 2; ++mi)
#pragma unroll
        for (int nt = 0; nt < 4; ++nt)
#pragma unroll
            for (int r = 0; r < 4; ++r)
                A_l[(mi * 16 + quad * 4 + r) * ST_A + 64 + w * 64 + nt * 16 + m] =
                    acc[mi][nt][r];
    __syncthreads();

    // conv: lane owns row b_l = lane&31; ig = w*2 + (lane>>5) + 8k.
    int b_l = lane & 31;
    int half = lane >> 5;
    size_t obase = ((size_t)d * 512 + bt2 * 32 + b_l) * 256;
#pragma unroll 1
    for (int k = 0; k < 2; ++k) {
        int ig = w * 2 + half + 8 * k;
        int i0 = ig * 16;
        float c16[16];
#pragma unroll
        for (int ii = 0; ii < 16; ++ii) c16[ii] = 0.f;
        float w24[24];
#pragma unroll
        for (int j6 = 0; j6 < 6; ++j6)
            *(float4*)&w24[j6 * 4] = *(float4*)&A_l[b_l * ST_A + i0 + 56 + j6 * 4];
        int P = 4 * w + 16 * k + 4;        // wave-uniform; overrun masked by pad
#pragma unroll 1
        for (int p = 0; p < P; ++p) {
            float4 h0 = *(float4*)&h_l[p * 8];
            float4 h1 = *(float4*)&h_l[p * 8 + 4];
            float hv[8] = {h0.x, h0.y, h0.z, h0.w, h1.x, h1.y, h1.z, h1.w};
#pragma unroll
            for (int q = 0; q < 8; ++q)
#pragma unroll
                for (int ii = 0; ii < 16; ++ii)
                    c16[ii] += hv[q] * w24[ii + 8 - q];
#pragma unroll
            for (int j = 23; j >= 8; --j) w24[j] = w24[j - 8];
            if (p + 1 < P) {
                int nb = b_l * ST_A + i0 + 48 - p * 8;   // >= 32: in-bounds
                *(float4*)&w24[0] = *(float4*)&A_l[nb];
                *(float4*)&w24[4] = *(float4*)&A_l[nb + 4];
            }
        }
#pragma unroll
        for (int j4 = 0; j4 < 4; ++j4) {
            float4 o;
            o.x = c16[j4 * 4 + 0] + hb_l[i0 + j4 * 4 + 0];
            o.y = c16[j4 * 4 + 1] + hb_l[i0 + j4 * 4 + 1];
            o.z = c16[j4 * 4 + 2] + hb_l[i0 + j4 * 4 + 2];
            o.w = c16[j4 * 4 + 3] + hb_l[i0 + j4 * 4 + 3];
            *(float4*)(Og + obase + i0 + j4 * 4) = o;
        }
    }
}

// ---------------- k_outT: Og[d][b][i] -> out[b][i][d] ----------------
// One block per b. Full-line coalesced on both global sides; LDS [d][i]
// stride 260 (b128 writes at 8-phase floor; scalar read gather 4-way).
__global__ __launch_bounds__(256) void k_outT(const float* __restrict__ Og,
                                              float* __restrict__ out) {
    __shared__ float sm[32 * 260];   // 33.3 KB
    int b = blockIdx.x;
    int tid = threadIdx.x;
#pragma unroll
    for (int it = 0; it < 8; ++it) {
        int lin = tid + it * 256;          // 0..2047 = 32 d x 64 iq
        int iq = lin & 63, d = lin >> 6;
        float4 v = *(const float4*)(Og + ((size_t)d * 512 + b) * 256 + iq * 4);
        *(float4*)&sm[d * 260 + iq * 4] = v;
    }
    __syncthreads();
#pragma unroll
    for (int it = 0; it < 8; ++it) {
        int lin = tid + it * 256;          // 0..2047 = 8 dq x 256 i
        int dq = lin & 7, i = lin >> 3;
        float4 o;
        o.x = sm[(dq * 4 + 0) * 260 + i];
        o.y = sm[(dq * 4 + 1) * 260 + i];
        o.z = sm[(dq * 4 + 2) * 260 + i];
        o.w = sm[(dq * 4 + 3) * 260 + i];
        *(float4*)(out + ((size_t)b * 256 + i) * 32 + dq * 4) = o;
    }
}

extern "C" void kernel_launch(void* const* d_in, const int* in_sizes, int n_in,
                              void* d_out, int out_size, void* d_ws, size_t ws_size,
                              hipStream_t stream) {
    const float* y_c  = (const float*)d_in[0];   // [512][2048][32]
    const float* W    = (const float*)d_in[1];   // [2048][32]
    const float* bias = (const float*)d_in[2];   // [32]
    float* out = (float*)d_out;                  // [512][256][32]

    char* ws = (char*)d_ws;
    ushort* Af  = (ushort*)(ws);
    ushort* Bf  = (ushort*)(ws + 67108864);
    float*  Og  = (float*) (ws + 100663296);     // [32][512][256]
    float*  h_g = (float*) (ws + 117440512);
    float*  Hb  = (float*) (ws + 117473280);
    float*  Wt  = (float*) (ws + 117506048);     // [32][2048]

    k_wt   <<<16, 256, 0, stream>>>(W, Wt);
    k_trans<<<dim3(32, 32), 256, 0, stream>>>(y_c, Af);
    k_bfrag<<<dim3(64, 32), 256, 0, stream>>>(Wt, Bf);
    k1_h   <<<32, 64, 0, stream>>>(W, bias, h_g, Hb);
    k_fused<<<512, 256, 0, stream>>>(Af, Bf, h_g, Hb, Og);
    k_outT <<<512, 256, 0, stream>>>(Og, out);
}

// Round 6
// 322.780 us; speedup vs baseline: 1.6630x; 1.0264x over previous
//
#include <hip/hip_runtime.h>

// Autoregressive linear model via LTI decomposition + bf16 MFMA:
//   Araw[b,i,d] = sum_t y[b,t,d] * W[t-i,d]          (k_fused GEMM phase, MFMA)
//   h_d: impulse response of out_i = A_i + sum c_m out_{i-m}, c_m = W[2048-m]
//   out[b,i,d]  = sum_{m<=i} h_d[m]*Araw[b,i-m,d] + bias_d * cumsum(h_d)[i]
//
// R6: Toeplitz B fragments DEDUPLICATED. frag(kt,nt) depends only on
// u = 2*kt - nt + 15 (142 unique frags/d, 145 KB/d vs 1 MiB expanded).
// Per-XCD B working set 568 KB -> L2-resident under the A stream; kills the
// ~512 MiB of B HBM re-reads that bounded R5's k_fused. Everything else
// identical to R5.
//
// ws layout (bytes):
//   Af  [32][8][64][4][64][8] bf16 @ 0         (67,108,864)  A fragments
//   Bf  [32][142][64][8] bf16    @ 67108864    (4,653,056)   unique B frags
//   Og  [32][512][256] f32       @ 71761920    (16,777,216)  pre-transpose out
//   h_g [32][256] f32            @ 88539136    (32,768)
//   Hb  [32][256] f32            @ 88571904    (32,768)
//   Wt  [32][2048] f32           @ 88604672    (262,144)
// total ~84.9 MiB (ws is 512 MiB)

#define L_SZ   2048
#define D_SZ   32
#define NI_SZ  256
#define ST_A   324     // A_l row stride (f32): 64 front zero-pad + 256 + 4
#define NU     142     // unique B fragments per d

using frag_ab = __attribute__((ext_vector_type(8))) short;   // 8 bf16
using f32x4v  = __attribute__((ext_vector_type(4))) float;

__device__ inline ushort f2bf(float x) {
    uint32_t u = __float_as_uint(x);
    return (ushort)((u + 0x7fffu + ((u >> 16) & 1u)) >> 16);   // RTNE
}

// ---------------- k_wt: W[t][d] -> Wt[d][t] (256 KiB, tiny) ----------------
__global__ __launch_bounds__(256) void k_wt(const float* __restrict__ W,
                                            float* __restrict__ Wt) {
    __shared__ float sm[32 * 132];
    int t0 = blockIdx.x * 128;
    int tid = threadIdx.x;
#pragma unroll
    for (int it = 0; it < 4; ++it) {
        int lin = tid + it * 256;          // 0..1023 = 8 dq x 128 tt
        int dq = lin & 7, tt = lin >> 3;
        float4 v = *(const float4*)(W + (size_t)(t0 + tt) * 32 + dq * 4);
        sm[(dq * 4 + 0) * 132 + tt] = v.x;
        sm[(dq * 4 + 1) * 132 + tt] = v.y;
        sm[(dq * 4 + 2) * 132 + tt] = v.z;
        sm[(dq * 4 + 3) * 132 + tt] = v.w;
    }
    __syncthreads();
#pragma unroll
    for (int it = 0; it < 4; ++it) {
        int lin = tid + it * 256;          // 32 tc x 32 d
        int tc = lin & 31, d = lin >> 5;
        float4 v = *(float4*)&sm[d * 132 + tc * 4];
        *(float4*)(Wt + (size_t)d * 2048 + t0 + tc * 4) = v;
    }
}

// ---------------- k_trans: Y[b][t][d] f32 -> Af fragment blobs ----------------
// (unchanged: register-transpose + b128 swizzled LDS, conflict-free)
__global__ __launch_bounds__(256) void k_trans(const float* __restrict__ Y,
                                               ushort* __restrict__ Af) {
    __shared__ ushort sm[512 * 64];   // 64 KB
    int bq = blockIdx.x, tq = blockIdx.y;
    int b0 = bq * 16, t0 = tq * 64;
    int tid = threadIdx.x;
#pragma unroll
    for (int it = 0; it < 4; ++it) {
        int g = tid + it * 256;
        int dq = g & 7, bb = (g >> 3) & 15, tg = g >> 7;
        float4 v[8];
#pragma unroll
        for (int q = 0; q < 8; ++q)
            v[q] = *(const float4*)(Y + ((size_t)(b0 + bb) * L_SZ + t0 + tg * 8 + q) * D_SZ + dq * 4);
#pragma unroll
        for (int c = 0; c < 4; ++c) {
            int row = (dq * 4 + c) * 16 + bb;
            int key = (row ^ (row >> 3)) & 7;
            uint4 u;
            u.x = (uint)f2bf((&v[0].x)[c]) | ((uint)f2bf((&v[1].x)[c]) << 16);
            u.y = (uint)f2bf((&v[2].x)[c]) | ((uint)f2bf((&v[3].x)[c]) << 16);
            u.z = (uint)f2bf((&v[4].x)[c]) | ((uint)f2bf((&v[5].x)[c]) << 16);
            u.w = (uint)f2bf((&v[6].x)[c]) | ((uint)f2bf((&v[7].x)[c]) << 16);
            *(uint4*)&sm[row * 64 + ((tg ^ key) * 8)] = u;
        }
    }
    __syncthreads();
    int wv = tid >> 6, lane = tid & 63;
    int m = lane & 15, quad = lane >> 4;
    int bt = bq >> 2, mt = bq & 3;
#pragma unroll
    for (int j = 0; j < 16; ++j) {
        int fi = wv * 16 + j;              // 0..63 = 32 d x 2 ktl
        int d = fi >> 1, ktl = fi & 1;
        int row = d * 16 + m;
        int key = (row ^ (row >> 3)) & 7;
        int cn = ktl * 4 + quad;
        uint4 u = *(uint4*)&sm[row * 64 + ((cn ^ key) * 8)];
        int ktg = tq * 2 + ktl;
        size_t off = ((((size_t)(d * 8 + bt) * 64 + ktg) * 4 + mt) * 64 + lane) * 8;
        *(uint4*)(Af + off) = u;
    }
}

// ---------------- k_bfrag: UNIQUE Toeplitz B fragments ----------------
// u = 2*kt - nt + 15 in [0,142). Frag value(lane, j) = w[16*(u-15) +
// quad*8 + j - n], zero-clamped. One 64-thread block per (u, d).
__global__ __launch_bounds__(64) void k_bfrag(const float* __restrict__ Wt,
                                              ushort* __restrict__ Bf) {
    __shared__ float wl[48];
    int u = blockIdx.x, d = blockIdx.y;
    int lane = threadIdx.x;
    int t0 = 16 * u - 255;                 // wl[s] = w[t0 + s], s in [0,48)
    if (lane < 48) {
        int t = t0 + lane;
        wl[lane] = (t >= 0 && t < L_SZ) ? Wt[(size_t)d * 2048 + t] : 0.f;
    }
    __syncthreads();
    int n = lane & 15, quad = lane >> 4;
    int base = 15 + quad * 8 - n;          // in [0,39]; +j up to 46
    ushort s[8];
#pragma unroll
    for (int j = 0; j < 8; ++j) s[j] = f2bf(wl[base + j]);
    uint4 uu;
    uu.x = (uint)s[0] | ((uint)s[1] << 16);
    uu.y = (uint)s[2] | ((uint)s[3] << 16);
    uu.z = (uint)s[4] | ((uint)s[5] << 16);
    uu.w = (uint)s[6] | ((uint)s[7] << 16);
    *(uint4*)(Bf + ((size_t)(d * NU + u) * 64 + lane) * 8) = uu;
}

// ---------------- k1: impulse response h + Hb = bias*cumsum(h) ----------------
__global__ __launch_bounds__(64) void k1_h(const float* __restrict__ W,
                                           const float* __restrict__ bias,
                                           float* __restrict__ h_g,
                                           float* __restrict__ Hb) {
    int d = blockIdx.x;
    int lane = threadIdx.x;
    __shared__ float c_l[256];
    __shared__ float h_l[256];
#pragma unroll
    for (int k = 0; k < 4; ++k) {
        int m = lane + 64 * k;
        c_l[m] = (m >= 1) ? W[(L_SZ - m) * D_SZ + d] : 0.f;
    }
    __syncthreads();
    float s0 = 0.f, s1 = 0.f, s2 = 0.f, s3 = 0.f;
    for (int i = 0; i < 256; ++i) {
        int slot = i >> 6;
        float v = (slot == 0) ? s0 : (slot == 1) ? s1 : (slot == 2) ? s2 : s3;
        float hv = (i == 0) ? 1.f : __shfl(v, i & 63, 64);
        int j;
        j = lane;        if (j > i) s0 += c_l[j - i] * hv;
        j = lane + 64;   if (j > i) s1 += c_l[j - i] * hv;
        j = lane + 128;  if (j > i) s2 += c_l[j - i] * hv;
        j = lane + 192;  if (j > i) s3 += c_l[j - i] * hv;
    }
    float h0 = (lane == 0) ? 1.f : s0;
    h_g[d * 256 + lane]       = h0;
    h_g[d * 256 + lane + 64]  = s1;
    h_g[d * 256 + lane + 128] = s2;
    h_g[d * 256 + lane + 192] = s3;
    h_l[lane] = h0; h_l[lane + 64] = s1; h_l[lane + 128] = s2; h_l[lane + 192] = s3;
    __syncthreads();
    float bv = bias[d];
    float S[4] = {0.f, 0.f, 0.f, 0.f};
    for (int m = 0; m < 256; ++m) {
        float hm = h_l[m];
#pragma unroll
        for (int k = 0; k < 4; ++k)
            if (m <= lane + 64 * k) S[k] += hm;
    }
#pragma unroll
    for (int k = 0; k < 4; ++k)
        Hb[d * 256 + lane + 64 * k] = bv * S[k];
}

// ---------------- k_fused: GEMM (MFMA) + IIR conv, one block per (d, 32b) ---
// grid 512: d = (idx&7)*4 + ((idx>>3)&3)  [XCD-swizzle: same-d -> same XCD],
// bt2 = idx>>5. B frags via dedup index u = 2*ktl - nt + 15 (L2-resident).
__global__ __launch_bounds__(256, 2) void k_fused(const ushort* __restrict__ Af,
                                                  const ushort* __restrict__ Bf,
                                                  const float* __restrict__ h_g,
                                                  const float* __restrict__ Hb,
                                                  float* __restrict__ Og) {
    __shared__ float A_l[32 * ST_A];   // 41.5 KB
    __shared__ float h_l[256];
    __shared__ float hb_l[256];
    int idx = blockIdx.x;
    int d   = (idx & 7) * 4 + ((idx >> 3) & 3);
    int bt2 = idx >> 5;                 // 0..15
    int bt  = bt2 >> 1, msel = (bt2 & 1) * 2;
    int tid = threadIdx.x, w = tid >> 6, lane = tid & 63;
    int m = lane & 15, quad = lane >> 4;

    h_l[tid]  = h_g[d * 256 + tid];
    hb_l[tid] = Hb[d * 256 + tid];
    {
        int r = tid >> 3, c = (tid & 7) * 8;
#pragma unroll
        for (int k = 0; k < 8; ++k) A_l[r * ST_A + c + k] = 0.f;
    }

    const ushort* Ap = Af + ((size_t)(d * 8 + bt) * 256 + msel) * 512 + (size_t)lane * 8;
    const ushort* Bq = Bf + ((size_t)(d * NU + 15 - w * 4)) * 512 + (size_t)lane * 8;

    f32x4v acc[2][4];
#pragma unroll
    for (int mi = 0; mi < 2; ++mi)
#pragma unroll
        for (int nt = 0; nt < 4; ++nt) acc[mi][nt] = (f32x4v){0.f, 0.f, 0.f, 0.f};

    frag_ab a[4][2], bb[4][4];
#define LOADG(s, ktl) { _Pragma("unroll") for (int mi = 0; mi < 2; ++mi) \
        a[s][mi] = *(const frag_ab*)(Ap + (size_t)((ktl) * 4 + mi) * 512); \
    _Pragma("unroll") for (int nt = 0; nt < 4; ++nt) \
        bb[s][nt] = *(const frag_ab*)(Bq + ((ptrdiff_t)(2 * (ktl)) - nt) * 512); }
#define MFMA_G(s) { _Pragma("unroll") for (int mi = 0; mi < 2; ++mi) \
        _Pragma("unroll") for (int nt = 0; nt < 4; ++nt) \
        acc[mi][nt] = __builtin_amdgcn_mfma_f32_16x16x32_bf16(a[s][mi], bb[s][nt], acc[mi][nt], 0, 0, 0); }

#pragma unroll
    for (int pf = 0; pf < 4; ++pf) LOADG(pf, pf);
#pragma unroll 1
    for (int kt4 = 0; kt4 < 15; ++kt4) {
#pragma unroll
        for (int s = 0; s < 4; ++s) {
            MFMA_G(s);
            LOADG(s, kt4 * 4 + s + 4);
        }
    }
#pragma unroll
    for (int s = 0; s < 4; ++s) MFMA_G(s);
#undef LOADG
#undef MFMA_G

    // acc -> LDS: b_local = mi*16+quad*4+r, i = w*64+nt*16+m
#pragma unroll
    for (int mi = 0; mi < 2; ++mi)
#pragma unroll
        for (int nt = 0; nt < 4; ++nt)
#pragma unroll
            for (int r = 0; r < 4; ++r)
                A_l[(mi * 16 + quad * 4 + r) * ST_A + 64 + w * 64 + nt * 16 + m] =
                    acc[mi][nt][r];
    __syncthreads();

    // conv: lane owns row b_l = lane&31; ig = w*2 + (lane>>5) + 8k.
    int b_l = lane & 31;
    int half = lane >> 5;
    size_t obase = ((size_t)d * 512 + bt2 * 32 + b_l) * 256;
#pragma unroll 1
    for (int k = 0; k < 2; ++k) {
        int ig = w * 2 + half + 8 * k;
        int i0 = ig * 16;
        float c16[16];
#pragma unroll
        for (int ii = 0; ii < 16; ++ii) c16[ii] = 0.f;
        float w24[24];
#pragma unroll
        for (int j6 = 0; j6 < 6; ++j6)
            *(float4*)&w24[j6 * 4] = *(float4*)&A_l[b_l * ST_A + i0 + 56 + j6 * 4];
        int P = 4 * w + 16 * k + 4;        // wave-uniform; overrun masked by pad
#pragma unroll 1
        for (int p = 0; p < P; ++p) {
            float4 h0 = *(float4*)&h_l[p * 8];
            float4 h1 = *(float4*)&h_l[p * 8 + 4];
            float hv[8] = {h0.x, h0.y, h0.z, h0.w, h1.x, h1.y, h1.z, h1.w};
#pragma unroll
            for (int q = 0; q < 8; ++q)
#pragma unroll
                for (int ii = 0; ii < 16; ++ii)
                    c16[ii] += hv[q] * w24[ii + 8 - q];
#pragma unroll
            for (int j = 23; j >= 8; --j) w24[j] = w24[j - 8];
            if (p + 1 < P) {
                int nb = b_l * ST_A + i0 + 48 - p * 8;   // >= 32: in-bounds
                *(float4*)&w24[0] = *(float4*)&A_l[nb];
                *(float4*)&w24[4] = *(float4*)&A_l[nb + 4];
            }
        }
#pragma unroll
        for (int j4 = 0; j4 < 4; ++j4) {
            float4 o;
            o.x = c16[j4 * 4 + 0] + hb_l[i0 + j4 * 4 + 0];
            o.y = c16[j4 * 4 + 1] + hb_l[i0 + j4 * 4 + 1];
            o.z = c16[j4 * 4 + 2] + hb_l[i0 + j4 * 4 + 2];
            o.w = c16[j4 * 4 + 3] + hb_l[i0 + j4 * 4 + 3];
            *(float4*)(Og + obase + i0 + j4 * 4) = o;
        }
    }
}

// ---------------- k_outT: Og[d][b][i] -> out[b][i][d] ----------------
__global__ __launch_bounds__(256) void k_outT(const float* __restrict__ Og,
                                              float* __restrict__ out) {
    __shared__ float sm[32 * 260];   // 33.3 KB
    int b = blockIdx.x;
    int tid = threadIdx.x;
#pragma unroll
    for (int it = 0; it < 8; ++it) {
        int lin = tid + it * 256;          // 0..2047 = 32 d x 64 iq
        int iq = lin & 63, d = lin >> 6;
        float4 v = *(const float4*)(Og + ((size_t)d * 512 + b) * 256 + iq * 4);
        *(float4*)&sm[d * 260 + iq * 4] = v;
    }
    __syncthreads();
#pragma unroll
    for (int it = 0; it < 8; ++it) {
        int lin = tid + it * 256;          // 0..2047 = 8 dq x 256 i
        int dq = lin & 7, i = lin >> 3;
        float4 o;
        o.x = sm[(dq * 4 + 0) * 260 + i];
        o.y = sm[(dq * 4 + 1) * 260 + i];
        o.z = sm[(dq * 4 + 2) * 260 + i];
        o.w = sm[(dq * 4 + 3) * 260 + i];
        *(float4*)(out + ((size_t)b * 256 + i) * 32 + dq * 4) = o;
    }
}

extern "C" void kernel_launch(void* const* d_in, const int* in_sizes, int n_in,
                              void* d_out, int out_size, void* d_ws, size_t ws_size,
                              hipStream_t stream) {
    const float* y_c  = (const float*)d_in[0];   // [512][2048][32]
    const float* W    = (const float*)d_in[1];   // [2048][32]
    const float* bias = (const float*)d_in[2];   // [32]
    float* out = (float*)d_out;                  // [512][256][32]

    char* ws = (char*)d_ws;
    ushort* Af  = (ushort*)(ws);
    ushort* Bf  = (ushort*)(ws + 67108864);
    float*  Og  = (float*) (ws + 71761920);      // [32][512][256]
    float*  h_g = (float*) (ws + 88539136);
    float*  Hb  = (float*) (ws + 88571904);
    float*  Wt  = (float*) (ws + 88604672);      // [32][2048]

    k_wt   <<<16, 256, 0, stream>>>(W, Wt);
    k_trans<<<dim3(32, 32), 256, 0, stream>>>(y_c, Af);
    k_bfrag<<<dim3(NU, 32), 64, 0, stream>>>(Wt, Bf);
    k1_h   <<<32, 64, 0, stream>>>(W, bias, h_g, Hb);
    k_fused<<<512, 256, 0, stream>>>(Af, Bf, h_g, Hb, Og);
    k_outT <<<512, 256, 0, stream>>>(Og, out);
}